// Round 17
// baseline (281.310 us; speedup 1.0000x reference)
//
#include <hip/hip_runtime.h>

#define N_NODES 100000
#define N_EDGES 1600000
#define D 64
#define NBUCK 391          // ceil(N_NODES/256) buckets of 256 dst
#define GBE 391            // edge-pass grid: ceil(N_EDGES/4096)
#define EPB 4096           // edges per block in binA/binC
#define DCAP 6144          // per-bucket capacity (mean 4096, sigma 64: +32 sigma)
#define NTILES 6250        // N_NODES / 16

typedef __attribute__((ext_vector_type(8))) short bf16x8;
typedef __attribute__((ext_vector_type(4))) float f32x4;

// ---------------- bf16 helpers ----------------
__device__ __forceinline__ unsigned short f2bf(float f) {
    unsigned int i = __float_as_uint(f);
    i += 0x7FFFu + ((i >> 16) & 1u);   // RNE
    return (unsigned short)(i >> 16);
}
// fma 8 bf16 channels packed in uint4 into a[0..7]
__device__ __forceinline__ void fma8(float* a, uint4 v, float wv) {
    a[0] = fmaf(wv, __uint_as_float(v.x << 16), a[0]);
    a[1] = fmaf(wv, __uint_as_float(v.x & 0xFFFF0000u), a[1]);
    a[2] = fmaf(wv, __uint_as_float(v.y << 16), a[2]);
    a[3] = fmaf(wv, __uint_as_float(v.y & 0xFFFF0000u), a[3]);
    a[4] = fmaf(wv, __uint_as_float(v.z << 16), a[4]);
    a[5] = fmaf(wv, __uint_as_float(v.z & 0xFFFF0000u), a[5]);
    a[6] = fmaf(wv, __uint_as_float(v.w << 16), a[6]);
    a[7] = fmaf(wv, __uint_as_float(v.w & 0xFFFF0000u), a[7]);
}

// ---------------- radix-binned CSR build (no global atomics on data) ----------

__global__ void binA(const int* __restrict__ col, int* __restrict__ histT) {
    __shared__ int h[NBUCK];
    int t = threadIdx.x;
    for (int i = t; i < NBUCK; i += 256) h[i] = 0;
    __syncthreads();
    int e0 = blockIdx.x * EPB;
    for (int i = t; i < EPB; i += 256) {
        int e = e0 + i;
        if (e < N_EDGES) atomicAdd(&h[col[e] >> 8], 1);
    }
    __syncthreads();
    for (int i = t; i < NBUCK; i += 256) histT[i * GBE + blockIdx.x] = h[i];
}

// B: per-row scan across blocks + (last finishing block) scan of rowtot -> bucketOff
__global__ void binB(int* __restrict__ histT, int* __restrict__ rowtot,
                     int* __restrict__ bucketOff, int* __restrict__ done) {
    __shared__ int s[512];
    __shared__ int lastflag;
    int b = blockIdx.x, tid = threadIdx.x;
    int v = (tid < GBE) ? histT[b * GBE + tid] : 0;
    s[tid] = v;
    __syncthreads();
    for (int o = 1; o < 512; o <<= 1) {
        int t = (tid >= o) ? s[tid - o] : 0;
        __syncthreads();
        s[tid] += t;
        __syncthreads();
    }
    if (tid < GBE) histT[b * GBE + tid] = s[tid] - v;   // exclusive
    if (tid == 511) atomicExch(&rowtot[b], s[511]);     // device-scope publish
    __syncthreads();
    if (tid == 0) {
        __threadfence();
        lastflag = (atomicAdd(done, 1) == NBUCK - 1);
    }
    __syncthreads();
    if (lastflag) {                                     // last block scans rowtot
        int rv = (tid < NBUCK) ? atomicAdd(&rowtot[tid], 0) : 0;  // coherent read
        s[tid] = rv;
        __syncthreads();
        for (int o = 1; o < 512; o <<= 1) {
            int t = (tid >= o) ? s[tid - o] : 0;
            __syncthreads();
            s[tid] += t;
            __syncthreads();
        }
        if (tid < NBUCK) bucketOff[tid] = s[tid] - rv;  // exclusive
        if (tid == 0) bucketOff[NBUCK] = N_EDGES;
    }
}

// C: partition edges into bucket-contiguous part_sw{src|dlo<<24, w}
__global__ void binC(const int* __restrict__ row, const int* __restrict__ col,
                     const float* __restrict__ w, const int* __restrict__ histT,
                     const int* __restrict__ bucketOff, int2* __restrict__ part_sw) {
    __shared__ int cur[NBUCK];
    int t = threadIdx.x;
    for (int i = t; i < NBUCK; i += 256)
        cur[i] = bucketOff[i] + histT[i * GBE + blockIdx.x];
    __syncthreads();
    int e0 = blockIdx.x * EPB;
    for (int i = t; i < EPB; i += 256) {
        int e = e0 + i;
        if (e >= N_EDGES) continue;
        int c = col[e];
        int pos = atomicAdd(&cur[c >> 8], 1);       // LDS atomic
        int2 p;
        p.x = (int)((unsigned)row[e] | ((unsigned)(c & 255) << 24));  // src<2^17
        p.y = __float_as_int(w[e]);
        part_sw[pos] = p;
    }
}

// D: per-bucket CSR built from an LDS-cached bucket (part_sw read ONCE);
// emits epack + base + dinv + prescaled xsb
__global__ void binD(const int2* __restrict__ part_sw, const int* __restrict__ bucketOff,
                     const float4* __restrict__ x4, int2* __restrict__ epack,
                     int* __restrict__ base, float* __restrict__ dinv,
                     ushort4* __restrict__ xsb4) {
    __shared__ int2 sw[DCAP];        // 48 KB: whole bucket cached
    __shared__ int hist[256];
    __shared__ int scanb[256];
    __shared__ int cur[256];
    __shared__ float wsum[256];
    int b = blockIdx.x, t = threadIdx.x;
    int s0 = bucketOff[b], m = bucketOff[b + 1] - s0;
    hist[t] = 0;
    wsum[t] = 0.0f;
    __syncthreads();
    for (int i = t; i < m; i += 256) {
        int2 p = part_sw[s0 + i];               // single global read of bucket
        sw[i] = p;
        atomicAdd(&hist[(unsigned)p.x >> 24], 1);
    }
    __syncthreads();
    // parallel exclusive scan of hist
    int v = hist[t];
    scanb[t] = v;
    __syncthreads();
    for (int o = 1; o < 256; o <<= 1) {
        int tv = (t >= o) ? scanb[t - o] : 0;
        __syncthreads();
        scanb[t] += tv;
        __syncthreads();
    }
    int excl = scanb[t] - v;
    cur[t] = excl;
    int dst = b * 256 + t;
    if (dst < N_NODES) base[dst] = s0 + excl;
    if (b == NBUCK - 1 && t == 0) base[N_NODES] = N_EDGES;
    __syncthreads();
    for (int i = t; i < m; i += 256) {
        int2 p = sw[i];                         // from LDS
        int dl = (int)((unsigned)p.x >> 24);
        int pos = s0 + atomicAdd(&cur[dl], 1);  // LDS atomic
        int2 q;
        q.x = (int)((unsigned)p.x & 0xFFFFFFu);
        q.y = p.y;
        epack[pos] = q;                         // scatter within 48KB bucket (L2-local)
        atomicAdd(&wsum[dl], __int_as_float(p.y));  // LDS float atomic
    }
    __syncthreads();
    float di = 0.0f;
    if (dst < N_NODES) {
        di = rsqrtf(1.0f + wsum[t]);
        dinv[dst] = di;
    }
    wsum[t] = di;                 // own-slot overwrite, no race
    __syncthreads();
    // fused prescale: xsb[node][d] = bf16(dinv[node] * x[node][d])
    int nvalid = N_NODES - b * 256;
#pragma unroll
    for (int i = 0; i < 16; ++i) {
        int gid = t + i * 256;        // float4 index within 256x16 tile
        int r = gid >> 4, ch = gid & 15;
        if (r < nvalid) {
            float s = wsum[r];
            size_t fidx = (size_t)(b * 256 + r) * 16 + ch;
            float4 xv = x4[fidx];
            ushort4 o;
            o.x = f2bf(s * xv.x); o.y = f2bf(s * xv.y);
            o.z = f2bf(s * xv.z); o.w = f2bf(s * xv.w);
            xsb4[fidx] = o;
        }
    }
}

// ---------------- fused layer (8 waves x 1 pair + MFMA epilogue) ---------------
// Block = one 16-node tile, now 512 threads = 8 WAVES; wave w aggregates only
// nodes 2w,2w+1 (one pair, 2 chains x unroll-2 = 4 gathers in flight, r15 body).
// Same grid, same 4 blocks/CU -> IDENTICAL L2 footprint (r16 falsifier confirmed
// 4 blocks/CU optimal), but 32 waves/CU instead of 16: 2x outstanding gathers,
// half the per-wave critical path. Waves 0-3 run the MFMA epilogue; 4-7 exit.
// VGPR must be <=64 for 8 waves/EU (r15 body compiled at 48).
template <bool LAST>
__global__ __launch_bounds__(512, 8)
void gcn_layer(const unsigned short* __restrict__ xsb, const float* __restrict__ W,
               const float* __restrict__ b, const float* __restrict__ dinv,
               const int2* __restrict__ epack, const int* __restrict__ base,
               unsigned short* __restrict__ hb_out, float* __restrict__ f_out) {
    __shared__ unsigned short T[16 * 72];       // agg rows bf16, row-padded
    int t = threadIdx.x;
    int lane  = t & 63;
    int wid   = t >> 6;                  // 0..7
    int g     = lane >> 3;               // edge slot 0..7
    int c8    = (lane & 7) * 8;          // channel octet
    int r16   = lane & 15;
    int halfk = (lane >> 4) * 8;         // k offset within K=32 chunk

    // B fragments direct from global W; waves 4-7 load duplicates (wid&3) to
    // avoid OOB — L2-hot, never used by them.
    int bcol = (wid & 3) * 16 + r16;
    bf16x8 bf0, bf1;
#pragma unroll
    for (int i = 0; i < 8; ++i) bf0[i] = (short)f2bf(W[(halfk + i) * D + bcol]);
#pragma unroll
    for (int i = 0; i < 8; ++i) bf1[i] = (short)f2bf(W[(halfk + 32 + i) * D + bcol]);
    float bias = b[bcol];

    int node0 = blockIdx.x * 16;
    // ---- this wave's single pair: nodes 2*wid, 2*wid+1 ----
    {
        int nA = node0 + wid * 2;
        int nB = nA + 1;
        float aA[8], aB[8];
#pragma unroll
        for (int q = 0; q < 8; ++q) { aA[q] = 0.0f; aB[q] = 0.0f; }
        if (g == 0) {                        // self term A (prescaled, w=1)
            uint4 sv = *(const uint4*)(xsb + (size_t)nA * D + c8);
            fma8(aA, sv, 1.0f);
        }
        if (g == 1) {                        // self term B
            uint4 sv = *(const uint4*)(xsb + (size_t)nB * D + c8);
            fma8(aB, sv, 1.0f);
        }
        int kA = base[nA], enA = base[nA + 1];
        int kB = enA,      enB = base[nB + 1];   // CSR rows are contiguous
        while (kA < enA || kB < enB) {
            bool dA0 = kA < enA,     dB0 = kB < enB;       // wave-uniform
            bool dA1 = kA + 8 < enA, dB1 = kB + 8 < enB;
            int2 pA0, pA1, pB0, pB1;
            uint4 vA0, vA1, vB0, vB1;
            float wA0 = 0.f, wA1 = 0.f, wB0 = 0.f, wB1 = 0.f;
            // phase 1: edge-record loads (sequential 8B, L2-hot)
            if (dA0) { int kg = kA + g;     int kc = (kg < enA) ? kg : enA - 1;
                       pA0 = epack[kc]; wA0 = (kg < enA) ? __int_as_float(pA0.y) : 0.f; }
            if (dB0) { int kg = kB + g;     int kc = (kg < enB) ? kg : enB - 1;
                       pB0 = epack[kc]; wB0 = (kg < enB) ? __int_as_float(pB0.y) : 0.f; }
            if (dA1) { int kg = kA + 8 + g; int kc = (kg < enA) ? kg : enA - 1;
                       pA1 = epack[kc]; wA1 = (kg < enA) ? __int_as_float(pA1.y) : 0.f; }
            if (dB1) { int kg = kB + 8 + g; int kc = (kg < enB) ? kg : enB - 1;
                       pB1 = epack[kc]; wB1 = (kg < enB) ? __int_as_float(pB1.y) : 0.f; }
            // phase 2: all four gathers issued back-to-back (4 in flight)
            if (dA0) vA0 = *(const uint4*)(xsb + (size_t)pA0.x * D + c8);
            if (dB0) vB0 = *(const uint4*)(xsb + (size_t)pB0.x * D + c8);
            if (dA1) vA1 = *(const uint4*)(xsb + (size_t)pA1.x * D + c8);
            if (dB1) vB1 = *(const uint4*)(xsb + (size_t)pB1.x * D + c8);
            // phase 3: consume in issue order
            if (dA0) fma8(aA, vA0, wA0);
            if (dB0) fma8(aB, vB0, wB0);
            if (dA1) fma8(aA, vA1, wA1);
            if (dB1) fma8(aB, vB1, wB1);
            kA += 16; kB += 16;
        }
#pragma unroll
        for (int q = 0; q < 8; ++q) {        // fold 8 edge-slot groups (both nodes)
            aA[q] += __shfl_xor(aA[q], 8);
            aB[q] += __shfl_xor(aB[q], 8);
            aA[q] += __shfl_xor(aA[q], 16);
            aB[q] += __shfl_xor(aB[q], 16);
            aA[q] += __shfl_xor(aA[q], 32);
            aB[q] += __shfl_xor(aB[q], 32);
        }
        // pack rows to bf16, park in LDS: lanes 0-7 -> row A, lanes 8-15 -> row B
        if (lane < 16) {
            float* a = (lane < 8) ? aA : aB;
            int nl = wid * 2 + (lane >> 3);
            int l8 = (lane & 7) * 8;
            uint4 pk;
            pk.x = ((unsigned)f2bf(a[1]) << 16) | f2bf(a[0]);
            pk.y = ((unsigned)f2bf(a[3]) << 16) | f2bf(a[2]);
            pk.z = ((unsigned)f2bf(a[5]) << 16) | f2bf(a[4]);
            pk.w = ((unsigned)f2bf(a[7]) << 16) | f2bf(a[6]);
            *(uint4*)&T[nl * 72 + l8] = pk;
        }
    }
    __syncthreads();                         // T tile complete (all 8 waves)
    if (wid >= 4) return;                    // waves 4-7 done
    // ---- MFMA: 16 nodes x 16 cols per wave (waves 0-3), K=64 in two chunks ----
    bf16x8 af0 = *(const bf16x8*)&T[r16 * 72 + halfk];
    bf16x8 af1 = *(const bf16x8*)&T[r16 * 72 + halfk + 32];
    f32x4 acc = {0.f, 0.f, 0.f, 0.f};
    acc = __builtin_amdgcn_mfma_f32_16x16x32_bf16(af0, bf0, acc, 0, 0, 0);
    acc = __builtin_amdgcn_mfma_f32_16x16x32_bf16(af1, bf1, acc, 0, 0, 0);
#pragma unroll
    for (int i = 0; i < 4; ++i) {
        int nr = (lane >> 4) * 4 + i;
        int node = node0 + nr;
        float s = dinv[node];
        float y = fmaxf(fmaf(s, acc[i], bias), 0.0f);
        size_t oidx = (size_t)node * D + bcol;
        if (LAST) f_out[oidx] = y;
        else      hb_out[oidx] = f2bf(s * y);   // prescale for next layer
    }
}

extern "C" void kernel_launch(void* const* d_in, const int* in_sizes, int n_in,
                              void* d_out, int out_size, void* d_ws, size_t ws_size,
                              hipStream_t stream) {
    const float* x       = (const float*)d_in[0];
    const int*   adj     = (const int*)d_in[1];    // [2][E]
    const float* adj_wts = (const float*)d_in[2];
    const float* W1      = (const float*)d_in[3];
    const float* b1      = (const float*)d_in[4];
    const float* W2      = (const float*)d_in[5];
    const float* b2      = (const float*)d_in[6];
    float* out = (float*)d_out;

    const int* row = adj;
    const int* col = adj + N_EDGES;

    // workspace layout (every block 16B-aligned)
    char* p = (char*)d_ws;
    int2* epack = (int2*)p;                   p += (size_t)N_EDGES * 8;       // 12.8MB
    unsigned short* xsb = (unsigned short*)p; p += (size_t)N_NODES * D * 2;   // 12.8MB
    unsigned short* hb  = (unsigned short*)p; p += (size_t)N_NODES * D * 2;   // 12.8MB
    int2* part_sw = (int2*)p;                 p += (size_t)N_EDGES * 8;       // 12.8MB
    int* histT = (int*)p;                     p += (size_t)(NBUCK * GBE + 3) / 4 * 4 * 4;
    int* rowtot = (int*)p;                    p += 392 * 4;
    int* bucketOff = (int*)p;                 p += 392 * 4;
    int* base = (int*)p;                      p += 100004 * 4;
    float* dinv = (float*)p;                  p += 100000 * 4;
    int* done = (int*)p;                      p += 4 * 4;

    // ---- CSR build: LDS-binned radix partition ----
    binA<<<GBE, 256, 0, stream>>>(col, histT);
    hipMemsetAsync(done, 0, 4, stream);               // reset binB's done counter
    binB<<<NBUCK, 512, 0, stream>>>(histT, rowtot, bucketOff, done);
    binC<<<GBE, 256, 0, stream>>>(row, col, adj_wts, histT, bucketOff, part_sw);
    binD<<<NBUCK, 256, 0, stream>>>(part_sw, bucketOff, (const float4*)x,
                                    epack, base, dinv, (ushort4*)xsb);

    // ---- fused layers (8-wave blocks, 1 pair/wave, MFMA epilogue) ----
    gcn_layer<false><<<NTILES, 512, 0, stream>>>(xsb, W1, b1, dinv, epack, base, hb, nullptr);
    gcn_layer<true ><<<NTILES, 512, 0, stream>>>(hb, W2, b2, dinv, epack, base, nullptr, out);
}

// Round 18
// 184.599 us; speedup vs baseline: 1.5239x; 1.5239x over previous
//
#include <hip/hip_runtime.h>

#define N_NODES 100000
#define N_EDGES 1600000
#define D 64
#define NBUCK 391          // ceil(N_NODES/256) buckets of 256 dst
#define GBE 391            // edge-pass grid: ceil(N_EDGES/4096)
#define EPB 4096           // edges per block in binA/binC
#define DCAP 6144          // per-bucket capacity (mean 4096, sigma 64: +32 sigma)
#define NTILES 6250        // N_NODES / 16

typedef __attribute__((ext_vector_type(8))) short bf16x8;
typedef __attribute__((ext_vector_type(4))) float f32x4;

// ---------------- bf16 helpers ----------------
__device__ __forceinline__ unsigned short f2bf(float f) {
    unsigned int i = __float_as_uint(f);
    i += 0x7FFFu + ((i >> 16) & 1u);   // RNE
    return (unsigned short)(i >> 16);
}
// fma 8 bf16 channels packed in uint4 into a[0..7]
__device__ __forceinline__ void fma8(float* a, uint4 v, float wv) {
    a[0] = fmaf(wv, __uint_as_float(v.x << 16), a[0]);
    a[1] = fmaf(wv, __uint_as_float(v.x & 0xFFFF0000u), a[1]);
    a[2] = fmaf(wv, __uint_as_float(v.y << 16), a[2]);
    a[3] = fmaf(wv, __uint_as_float(v.y & 0xFFFF0000u), a[3]);
    a[4] = fmaf(wv, __uint_as_float(v.z << 16), a[4]);
    a[5] = fmaf(wv, __uint_as_float(v.z & 0xFFFF0000u), a[5]);
    a[6] = fmaf(wv, __uint_as_float(v.w << 16), a[6]);
    a[7] = fmaf(wv, __uint_as_float(v.w & 0xFFFF0000u), a[7]);
}

// ---------------- radix-binned CSR build (no global atomics on data) ----------

__global__ void binA(const int* __restrict__ col, int* __restrict__ histT) {
    __shared__ int h[NBUCK];
    int t = threadIdx.x;
    for (int i = t; i < NBUCK; i += 256) h[i] = 0;
    __syncthreads();
    int e0 = blockIdx.x * EPB;
    for (int i = t; i < EPB; i += 256) {
        int e = e0 + i;
        if (e < N_EDGES) atomicAdd(&h[col[e] >> 8], 1);
    }
    __syncthreads();
    for (int i = t; i < NBUCK; i += 256) histT[i * GBE + blockIdx.x] = h[i];
}

// B: per-row scan across blocks + (last finishing block) scan of rowtot -> bucketOff
__global__ void binB(int* __restrict__ histT, int* __restrict__ rowtot,
                     int* __restrict__ bucketOff, int* __restrict__ done) {
    __shared__ int s[512];
    __shared__ int lastflag;
    int b = blockIdx.x, tid = threadIdx.x;
    int v = (tid < GBE) ? histT[b * GBE + tid] : 0;
    s[tid] = v;
    __syncthreads();
    for (int o = 1; o < 512; o <<= 1) {
        int t = (tid >= o) ? s[tid - o] : 0;
        __syncthreads();
        s[tid] += t;
        __syncthreads();
    }
    if (tid < GBE) histT[b * GBE + tid] = s[tid] - v;   // exclusive
    if (tid == 511) atomicExch(&rowtot[b], s[511]);     // device-scope publish
    __syncthreads();
    if (tid == 0) {
        __threadfence();
        lastflag = (atomicAdd(done, 1) == NBUCK - 1);
    }
    __syncthreads();
    if (lastflag) {                                     // last block scans rowtot
        int rv = (tid < NBUCK) ? atomicAdd(&rowtot[tid], 0) : 0;  // coherent read
        s[tid] = rv;
        __syncthreads();
        for (int o = 1; o < 512; o <<= 1) {
            int t = (tid >= o) ? s[tid - o] : 0;
            __syncthreads();
            s[tid] += t;
            __syncthreads();
        }
        if (tid < NBUCK) bucketOff[tid] = s[tid] - rv;  // exclusive
        if (tid == 0) bucketOff[NBUCK] = N_EDGES;
    }
}

// C: partition edges into bucket-contiguous part_sw{src|dlo<<24, w}
__global__ void binC(const int* __restrict__ row, const int* __restrict__ col,
                     const float* __restrict__ w, const int* __restrict__ histT,
                     const int* __restrict__ bucketOff, int2* __restrict__ part_sw) {
    __shared__ int cur[NBUCK];
    int t = threadIdx.x;
    for (int i = t; i < NBUCK; i += 256)
        cur[i] = bucketOff[i] + histT[i * GBE + blockIdx.x];
    __syncthreads();
    int e0 = blockIdx.x * EPB;
    for (int i = t; i < EPB; i += 256) {
        int e = e0 + i;
        if (e >= N_EDGES) continue;
        int c = col[e];
        int pos = atomicAdd(&cur[c >> 8], 1);       // LDS atomic
        int2 p;
        p.x = (int)((unsigned)row[e] | ((unsigned)(c & 255) << 24));  // src<2^17
        p.y = __float_as_int(w[e]);
        part_sw[pos] = p;
    }
}

// D: per-bucket CSR built from an LDS-cached bucket (part_sw read ONCE);
// emits epack + base + dinv + prescaled xsb
__global__ void binD(const int2* __restrict__ part_sw, const int* __restrict__ bucketOff,
                     const float4* __restrict__ x4, int2* __restrict__ epack,
                     int* __restrict__ base, float* __restrict__ dinv,
                     ushort4* __restrict__ xsb4) {
    __shared__ int2 sw[DCAP];        // 48 KB: whole bucket cached
    __shared__ int hist[256];
    __shared__ int scanb[256];
    __shared__ int cur[256];
    __shared__ float wsum[256];
    int b = blockIdx.x, t = threadIdx.x;
    int s0 = bucketOff[b], m = bucketOff[b + 1] - s0;
    hist[t] = 0;
    wsum[t] = 0.0f;
    __syncthreads();
    for (int i = t; i < m; i += 256) {
        int2 p = part_sw[s0 + i];               // single global read of bucket
        sw[i] = p;
        atomicAdd(&hist[(unsigned)p.x >> 24], 1);
    }
    __syncthreads();
    // parallel exclusive scan of hist
    int v = hist[t];
    scanb[t] = v;
    __syncthreads();
    for (int o = 1; o < 256; o <<= 1) {
        int tv = (t >= o) ? scanb[t - o] : 0;
        __syncthreads();
        scanb[t] += tv;
        __syncthreads();
    }
    int excl = scanb[t] - v;
    cur[t] = excl;
    int dst = b * 256 + t;
    if (dst < N_NODES) base[dst] = s0 + excl;
    if (b == NBUCK - 1 && t == 0) base[N_NODES] = N_EDGES;
    __syncthreads();
    for (int i = t; i < m; i += 256) {
        int2 p = sw[i];                         // from LDS
        int dl = (int)((unsigned)p.x >> 24);
        int pos = s0 + atomicAdd(&cur[dl], 1);  // LDS atomic
        int2 q;
        q.x = (int)((unsigned)p.x & 0xFFFFFFu);
        q.y = p.y;
        epack[pos] = q;                         // scatter within 48KB bucket (L2-local)
        atomicAdd(&wsum[dl], __int_as_float(p.y));  // LDS float atomic
    }
    __syncthreads();
    float di = 0.0f;
    if (dst < N_NODES) {
        di = rsqrtf(1.0f + wsum[t]);
        dinv[dst] = di;
    }
    wsum[t] = di;                 // own-slot overwrite, no race
    __syncthreads();
    // fused prescale: xsb[node][d] = bf16(dinv[node] * x[node][d])
    int nvalid = N_NODES - b * 256;
#pragma unroll
    for (int i = 0; i < 16; ++i) {
        int gid = t + i * 256;        // float4 index within 256x16 tile
        int r = gid >> 4, ch = gid & 15;
        if (r < nvalid) {
            float s = wsum[r];
            size_t fidx = (size_t)(b * 256 + r) * 16 + ch;
            float4 xv = x4[fidx];
            ushort4 o;
            o.x = f2bf(s * xv.x); o.y = f2bf(s * xv.y);
            o.z = f2bf(s * xv.z); o.w = f2bf(s * xv.w);
            xsb4[fidx] = o;
        }
    }
}

// ---------------- fused layer (r15 optimum: 2-chain x unroll-2 + MFMA) --------
// Block = one 16-node tile, 4 waves, 4 blocks/CU. Wave w aggregates nodes
// 4w..4w+3 as TWO chains; each loop iteration issues FOUR independent gathers
// (A0,B0,A1,B1 = 16 edges) before any consume -> 4 gathers in flight per wave.
// CONCURRENCY EQUILIBRIUM (r11/r15/r16/r17 mapped): ~64 outstanding 1KB
// gathers/CU is optimal; 6 blocks/CU (r16) and 8 waves/block (r17) both
// re-amplified FETCH/WRITE via L2 thrash. FETCH=88MB is ~86% of the 8-XCD
// replication floor (8 x 12.8MB table) — gather path at structural equilibrium.
template <bool LAST>
__global__ __launch_bounds__(256, 4)
void gcn_layer(const unsigned short* __restrict__ xsb, const float* __restrict__ W,
               const float* __restrict__ b, const float* __restrict__ dinv,
               const int2* __restrict__ epack, const int* __restrict__ base,
               unsigned short* __restrict__ hb_out, float* __restrict__ f_out) {
    __shared__ unsigned short T[16 * 72];       // agg rows bf16, row-padded
    int t = threadIdx.x;
    int lane  = t & 63;
    int wid   = t >> 6;
    int g     = lane >> 3;               // edge slot 0..7
    int c8    = (lane & 7) * 8;          // channel octet
    int r16   = lane & 15;
    int halfk = (lane >> 4) * 8;         // k offset within K=32 chunk

    // B fragments direct from global W (issued now, consumed at the end)
    int bcol = wid * 16 + r16;
    bf16x8 bf0, bf1;
#pragma unroll
    for (int i = 0; i < 8; ++i) bf0[i] = (short)f2bf(W[(halfk + i) * D + bcol]);
#pragma unroll
    for (int i = 0; i < 8; ++i) bf1[i] = (short)f2bf(W[(halfk + 32 + i) * D + bcol]);
    float bias = b[bcol];

    int node0 = blockIdx.x * 16;
    // ---- aggregate this wave's 4 nodes, as 2 chains x 2-unrolled pairs ----
    for (int jp = 0; jp < 2; ++jp) {
        int nA = node0 + wid * 4 + jp * 2;
        int nB = nA + 1;
        float aA[8], aB[8];
#pragma unroll
        for (int q = 0; q < 8; ++q) { aA[q] = 0.0f; aB[q] = 0.0f; }
        if (g == 0) {                        // self term A (prescaled, w=1)
            uint4 sv = *(const uint4*)(xsb + (size_t)nA * D + c8);
            fma8(aA, sv, 1.0f);
        }
        if (g == 1) {                        // self term B
            uint4 sv = *(const uint4*)(xsb + (size_t)nB * D + c8);
            fma8(aB, sv, 1.0f);
        }
        int kA = base[nA], enA = base[nA + 1];
        int kB = enA,      enB = base[nB + 1];   // CSR rows are contiguous
        while (kA < enA || kB < enB) {
            bool dA0 = kA < enA,     dB0 = kB < enB;       // wave-uniform
            bool dA1 = kA + 8 < enA, dB1 = kB + 8 < enB;
            int2 pA0, pA1, pB0, pB1;
            uint4 vA0, vA1, vB0, vB1;
            float wA0 = 0.f, wA1 = 0.f, wB0 = 0.f, wB1 = 0.f;
            // phase 1: edge-record loads (sequential 8B, L2-hot)
            if (dA0) { int kg = kA + g;     int kc = (kg < enA) ? kg : enA - 1;
                       pA0 = epack[kc]; wA0 = (kg < enA) ? __int_as_float(pA0.y) : 0.f; }
            if (dB0) { int kg = kB + g;     int kc = (kg < enB) ? kg : enB - 1;
                       pB0 = epack[kc]; wB0 = (kg < enB) ? __int_as_float(pB0.y) : 0.f; }
            if (dA1) { int kg = kA + 8 + g; int kc = (kg < enA) ? kg : enA - 1;
                       pA1 = epack[kc]; wA1 = (kg < enA) ? __int_as_float(pA1.y) : 0.f; }
            if (dB1) { int kg = kB + 8 + g; int kc = (kg < enB) ? kg : enB - 1;
                       pB1 = epack[kc]; wB1 = (kg < enB) ? __int_as_float(pB1.y) : 0.f; }
            // phase 2: all four gathers issued back-to-back (4 in flight)
            if (dA0) vA0 = *(const uint4*)(xsb + (size_t)pA0.x * D + c8);
            if (dB0) vB0 = *(const uint4*)(xsb + (size_t)pB0.x * D + c8);
            if (dA1) vA1 = *(const uint4*)(xsb + (size_t)pA1.x * D + c8);
            if (dB1) vB1 = *(const uint4*)(xsb + (size_t)pB1.x * D + c8);
            // phase 3: consume in issue order
            if (dA0) fma8(aA, vA0, wA0);
            if (dB0) fma8(aB, vB0, wB0);
            if (dA1) fma8(aA, vA1, wA1);
            if (dB1) fma8(aB, vB1, wB1);
            kA += 16; kB += 16;
        }
#pragma unroll
        for (int q = 0; q < 8; ++q) {        // fold 8 edge-slot groups (both nodes)
            aA[q] += __shfl_xor(aA[q], 8);
            aB[q] += __shfl_xor(aB[q], 8);
            aA[q] += __shfl_xor(aA[q], 16);
            aB[q] += __shfl_xor(aB[q], 16);
            aA[q] += __shfl_xor(aA[q], 32);
            aB[q] += __shfl_xor(aB[q], 32);
        }
        // pack rows to bf16, park in LDS: lanes 0-7 -> row A, lanes 8-15 -> row B
        if (lane < 16) {
            float* a = (lane < 8) ? aA : aB;
            int nl = wid * 4 + jp * 2 + (lane >> 3);
            int l8 = (lane & 7) * 8;
            uint4 pk;
            pk.x = ((unsigned)f2bf(a[1]) << 16) | f2bf(a[0]);
            pk.y = ((unsigned)f2bf(a[3]) << 16) | f2bf(a[2]);
            pk.z = ((unsigned)f2bf(a[5]) << 16) | f2bf(a[4]);
            pk.w = ((unsigned)f2bf(a[7]) << 16) | f2bf(a[6]);
            *(uint4*)&T[nl * 72 + l8] = pk;
        }
    }
    __syncthreads();                         // T tile complete
    // ---- MFMA: 16 nodes x 16 cols, K=64 in two chunks ----
    bf16x8 af0 = *(const bf16x8*)&T[r16 * 72 + halfk];
    bf16x8 af1 = *(const bf16x8*)&T[r16 * 72 + halfk + 32];
    f32x4 acc = {0.f, 0.f, 0.f, 0.f};
    acc = __builtin_amdgcn_mfma_f32_16x16x32_bf16(af0, bf0, acc, 0, 0, 0);
    acc = __builtin_amdgcn_mfma_f32_16x16x32_bf16(af1, bf1, acc, 0, 0, 0);
#pragma unroll
    for (int i = 0; i < 4; ++i) {
        int nr = (lane >> 4) * 4 + i;
        int node = node0 + nr;
        float s = dinv[node];
        float y = fmaxf(fmaf(s, acc[i], bias), 0.0f);
        size_t oidx = (size_t)node * D + bcol;
        if (LAST) f_out[oidx] = y;
        else      hb_out[oidx] = f2bf(s * y);   // prescale for next layer
    }
}

extern "C" void kernel_launch(void* const* d_in, const int* in_sizes, int n_in,
                              void* d_out, int out_size, void* d_ws, size_t ws_size,
                              hipStream_t stream) {
    const float* x       = (const float*)d_in[0];
    const int*   adj     = (const int*)d_in[1];    // [2][E]
    const float* adj_wts = (const float*)d_in[2];
    const float* W1      = (const float*)d_in[3];
    const float* b1      = (const float*)d_in[4];
    const float* W2      = (const float*)d_in[5];
    const float* b2      = (const float*)d_in[6];
    float* out = (float*)d_out;

    const int* row = adj;
    const int* col = adj + N_EDGES;

    // workspace layout (every block 16B-aligned)
    char* p = (char*)d_ws;
    int2* epack = (int2*)p;                   p += (size_t)N_EDGES * 8;       // 12.8MB
    unsigned short* xsb = (unsigned short*)p; p += (size_t)N_NODES * D * 2;   // 12.8MB
    unsigned short* hb  = (unsigned short*)p; p += (size_t)N_NODES * D * 2;   // 12.8MB
    int2* part_sw = (int2*)p;                 p += (size_t)N_EDGES * 8;       // 12.8MB
    int* histT = (int*)p;                     p += (size_t)(NBUCK * GBE + 3) / 4 * 4 * 4;
    int* rowtot = (int*)p;                    p += 392 * 4;
    int* bucketOff = (int*)p;                 p += 392 * 4;
    int* base = (int*)p;                      p += 100004 * 4;
    float* dinv = (float*)p;                  p += 100000 * 4;
    int* done = (int*)p;                      p += 4 * 4;

    // ---- CSR build: LDS-binned radix partition ----
    binA<<<GBE, 256, 0, stream>>>(col, histT);
    hipMemsetAsync(done, 0, 4, stream);               // reset binB's done counter
    binB<<<NBUCK, 512, 0, stream>>>(histT, rowtot, bucketOff, done);
    binC<<<GBE, 256, 0, stream>>>(row, col, adj_wts, histT, bucketOff, part_sw);
    binD<<<NBUCK, 256, 0, stream>>>(part_sw, bucketOff, (const float4*)x,
                                    epack, base, dinv, (ushort4*)xsb);

    // ---- fused layers (2-chain x unroll-2 gather agg + MFMA GEMM) ----
    gcn_layer<false><<<NTILES, 256, 0, stream>>>(xsb, W1, b1, dinv, epack, base, hb, nullptr);
    gcn_layer<true ><<<NTILES, 256, 0, stream>>>(hb, W2, b2, dinv, epack, base, nullptr, out);
}